// Round 3
// baseline (379.660 us; speedup 1.0000x reference)
//
#include <hip/hip_runtime.h>

// SVD predict + feature-concat kernel, round 3.
// 8 lanes per batch row; each lane owns two float4 chunks of the 64-float
// p-row and q-row (4 independent gather loads in flight per thread for
// latency hiding). Feature output is written with nontemporal stores so the
// 64 MB streaming write doesn't evict gather rows from L2/L3.
// Note: __builtin_nontemporal_store needs a NATIVE vector type, not HIP's
// float4 class — use ext_vector_type(4).
typedef float nfloat4 __attribute__((ext_vector_type(4)));

__global__ __launch_bounds__(256) void svd_predict_kernel(
    const int* __restrict__ user_item,
    const float* __restrict__ pu,
    const float* __restrict__ qi,
    const float* __restrict__ bu,
    const float* __restrict__ bi,
    const float* __restrict__ gm_ptr,
    float* __restrict__ out,
    int batch)
{
    const float gm = gm_ptr[0];
    const int lane8 = threadIdx.x & 7;
    const int row = (int)((blockIdx.x * blockDim.x + threadIdx.x) >> 3);
    if (row >= batch) return;

    const int uid = user_item[2 * row];
    const int iid = user_item[2 * row + 1];

    // issue all 4 gathers + 2 bias loads before any use
    const nfloat4* prow = (const nfloat4*)(pu + (size_t)uid * 64);
    const nfloat4* qrow = (const nfloat4*)(qi + (size_t)iid * 64);
    nfloat4 pv0 = prow[lane8];
    nfloat4 pv1 = prow[8 + lane8];
    nfloat4 qv0 = qrow[lane8];
    nfloat4 qv1 = qrow[8 + lane8];
    float bub = (lane8 == 0) ? bu[uid] : 0.0f;
    float bib = (lane8 == 0) ? bi[iid] : 0.0f;

    // features: out[batch + row*128 + {0..63 | 64..127}], streaming stores
    nfloat4* frow = (nfloat4*)(out + (size_t)batch + (size_t)row * 128);
    __builtin_nontemporal_store(pv0, frow + lane8);
    __builtin_nontemporal_store(pv1, frow + 8 + lane8);
    __builtin_nontemporal_store(qv0, frow + 16 + lane8);
    __builtin_nontemporal_store(qv1, frow + 24 + lane8);

    float s = pv0.x * qv0.x + pv0.y * qv0.y + pv0.z * qv0.z + pv0.w * qv0.w
            + pv1.x * qv1.x + pv1.y * qv1.y + pv1.z * qv1.z + pv1.w * qv1.w;
    // reduce across the 8-lane segment
    s += __shfl_down(s, 4, 8);
    s += __shfl_down(s, 2, 8);
    s += __shfl_down(s, 1, 8);

    if (lane8 == 0) {
        float pred = gm + bub + bib + s;
        pred = fminf(fmaxf(pred, 1.0f), 5.0f);
        __builtin_nontemporal_store(pred, out + row);
    }
}

extern "C" void kernel_launch(void* const* d_in, const int* in_sizes, int n_in,
                              void* d_out, int out_size, void* d_ws, size_t ws_size,
                              hipStream_t stream) {
    const int*   user_item = (const int*)d_in[0];
    const float* pu        = (const float*)d_in[1];
    const float* qi        = (const float*)d_in[2];
    const float* bu        = (const float*)d_in[3];
    const float* bi        = (const float*)d_in[4];
    const float* gm        = (const float*)d_in[5];
    float*       out       = (float*)d_out;

    const int batch = in_sizes[0] / 2;           // user_item is (BATCH, 2)
    const int rows_per_block = 256 / 8;          // 8 lanes per row
    const int blocks = (batch + rows_per_block - 1) / rows_per_block;

    svd_predict_kernel<<<blocks, 256, 0, stream>>>(
        user_item, pu, qi, bu, bi, gm, out, batch);
}